// Round 11
// baseline (102.631 us; speedup 1.0000x reference)
//
#include <hip/hip_runtime.h>
#include <cstddef>
#include <cstdint>

#define S_LEN 2048
#define D_DIM 512
#define NHEAD 4
#define DHEAD 128
#define BH_CNT 16
#define SCALE_QK 0.08838834764831845f

typedef _Float16 f16;
typedef _Float16 f16x8 __attribute__((ext_vector_type(8)));
typedef float f32x16 __attribute__((ext_vector_type(16)));

__device__ __forceinline__ unsigned pkh(float a, float b) {
  auto r = __builtin_amdgcn_cvt_pkrtz(a, b);   // __fp16 ext_vector_type(2)
  return __builtin_bit_cast(unsigned, r);
}

// ---------------- Kernel 1: gate preactivations ----------------
__global__ __launch_bounds__(256) void gate_kernel(
    const float* __restrict__ q, const float* __restrict__ k, const float* __restrict__ v,
    const float* __restrict__ Wi, const float* __restrict__ bi,
    const float* __restrict__ Wf, const float* __restrict__ bf,
    float* __restrict__ ipre, float* __restrict__ fpre)
{
  const int wave = threadIdx.x >> 6;
  const int lane = threadIdx.x & 63;
  const int pos  = blockIdx.x * 4 + wave;
  const int b = pos >> 11;
  const int s = pos & 2047;
  const float* qp = q + (size_t)pos * D_DIM;
  const float* kp = k + (size_t)pos * D_DIM;
  const float* vp = v + (size_t)pos * D_DIM;

  float acc[8] = {0.f,0.f,0.f,0.f,0.f,0.f,0.f,0.f};
  #pragma unroll
  for (int j = 0; j < 24; ++j) {
    int e = lane + (j << 6);
    float x;
    if (e < 512)       x = qp[e];
    else if (e < 1024) x = kp[e - 512];
    else               x = vp[e - 1024];
    #pragma unroll
    for (int h = 0; h < 4; ++h) {
      acc[h]     = fmaf(x, Wi[h * 1536 + e], acc[h]);
      acc[4 + h] = fmaf(x, Wf[h * 1536 + e], acc[4 + h]);
    }
  }
  #pragma unroll
  for (int off = 32; off > 0; off >>= 1) {
    #pragma unroll
    for (int a = 0; a < 8; ++a) acc[a] += __shfl_down(acc[a], off);
  }
  if (lane == 0) {
    #pragma unroll
    for (int h = 0; h < 4; ++h) {
      ipre[(size_t)(b * 4 + h) * S_LEN + s] = acc[h] + bi[h];
      fpre[(size_t)(b * 4 + h) * S_LEN + s] = acc[4 + h] + bf[h];
    }
  }
}

// ---------------- Kernel 2: single-pass register scans ----------------
__global__ __launch_bounds__(256) void scan_kernel(
    const float* __restrict__ ipre, const float* __restrict__ fpre,
    float* __restrict__ g_out, float* __restrict__ M_out,
    float* __restrict__ bsum_out, float* __restrict__ Gt_out)
{
  __shared__ float wsh[8];
  const int bh = blockIdx.x;
  const int tid = threadIdx.x, lane = tid & 63, wv = tid >> 6;
  const int base = tid * 8;
  const float* fp = fpre + (size_t)bh * S_LEN;
  const float* ip = ipre + (size_t)bh * S_LEN;

  float x[8], ls[8];
  float4 a0 = *(const float4*)(fp + base), a1 = *(const float4*)(fp + base + 4);
  x[0]=a0.x; x[1]=a0.y; x[2]=a0.z; x[3]=a0.w;
  x[4]=a1.x; x[5]=a1.y; x[6]=a1.z; x[7]=a1.w;
  float run = 0.f;
  #pragma unroll
  for (int i = 0; i < 8; ++i) {
    float lsv = fminf(x[i], 0.f) - log1pf(expf(-fabsf(x[i])));
    run += lsv; ls[i] = run;
  }
  float sc = run;
  #pragma unroll
  for (int off = 1; off < 64; off <<= 1) {
    float o = __shfl_up(sc, off);
    if (lane >= off) sc += o;
  }
  if (lane == 63) wsh[wv] = sc;
  __syncthreads();
  float woff = 0.f;
  #pragma unroll
  for (int u = 0; u < 4; ++u) if (u < wv) woff += wsh[u];
  const float ex = woff + (sc - run);

  float4 i0 = *(const float4*)(ip + base), i1 = *(const float4*)(ip + base + 4);
  float iv[8];
  iv[0]=i0.x; iv[1]=i0.y; iv[2]=i0.z; iv[3]=i0.w;
  iv[4]=i1.x; iv[5]=i1.y; iv[6]=i1.z; iv[7]=i1.w;
  float g[8], bc[8], pm[8];
  float runm = -3.0e38f;
  #pragma unroll
  for (int i = 0; i < 8; ++i) {
    bc[i] = ex + ls[i];
    g[i] = iv[i] - bc[i];
    runm = fmaxf(runm, g[i]);
    pm[i] = runm;
  }
  *(float4*)(bsum_out + (size_t)bh * S_LEN + base)     = make_float4(bc[0],bc[1],bc[2],bc[3]);
  *(float4*)(bsum_out + (size_t)bh * S_LEN + base + 4) = make_float4(bc[4],bc[5],bc[6],bc[7]);
  *(float4*)(g_out + (size_t)bh * S_LEN + base)        = make_float4(g[0],g[1],g[2],g[3]);
  *(float4*)(g_out + (size_t)bh * S_LEN + base + 4)    = make_float4(g[4],g[5],g[6],g[7]);

  float t8 = runm;
  t8 = fmaxf(t8, __shfl_xor(t8, 1));
  t8 = fmaxf(t8, __shfl_xor(t8, 2));
  t8 = fmaxf(t8, __shfl_xor(t8, 4));
  if ((tid & 7) == 0) Gt_out[bh * 32 + (tid >> 3)] = t8;

  float scm = runm;
  #pragma unroll
  for (int off = 1; off < 64; off <<= 1) {
    float o = __shfl_up(scm, off);
    if (lane >= off) scm = fmaxf(scm, o);
  }
  if (lane == 63) wsh[4 + wv] = scm;
  __syncthreads();
  float wmo = -3.0e38f;
  #pragma unroll
  for (int u = 0; u < 4; ++u) if (u < wv) wmo = fmaxf(wmo, wsh[4 + u]);
  float prev = __shfl_up(scm, 1);
  if (lane == 0) prev = -3.0e38f;
  const float exm = fmaxf(wmo, prev);
  float M[8];
  #pragma unroll
  for (int i = 0; i < 8; ++i) M[i] = fmaxf(exm, pm[i]);
  *(float4*)(M_out + (size_t)bh * S_LEN + base)     = make_float4(M[0],M[1],M[2],M[3]);
  *(float4*)(M_out + (size_t)bh * S_LEN + base + 4) = make_float4(M[4],M[5],M[6],M[7]);
}

// head-complementary bh pairing: XCD x serves pairA(x) (head 0/1) and
// pairB(x) (head 3/2) so per-XCD work is balanced despite head-dependent skip.
__device__ __forceinline__ int pairA(int x) { return (x >> 1) * 4 + (x & 1); }
__device__ __forceinline__ int pairB(int x) { return (x >> 1) * 4 + 3 - (x & 1); }

// ---------------- Kernel 3: fp16 conversion, fragment-linear, XCD-matched ----
// grid (8, 64): x = XCD slot; y<32 -> bh=pairA(x), kt=y; else bh=pairB(x).
// qhat/khat tile (bh,kt64), 16KB, 16B units: unit(((s>>5)*8+ks)*2+hi)*32+(s&31)
//   khat holds k * exp(g-Gt); qhat holds q * SCALE_QK
// vT tile: unit(((d>>5)*4+c)*2+hi2)*32+(d&31) holds v[s0..s0+8, d], s0=(2c+hi2)*8
__global__ __launch_bounds__(256) void convert_kernel(
    const float* __restrict__ q, const float* __restrict__ k, const float* __restrict__ v,
    const float* __restrict__ g_arr, const float* __restrict__ Gt_arr,
    char* __restrict__ qhat, char* __restrict__ khat, char* __restrict__ vT)
{
  const int x = blockIdx.x, y = blockIdx.y;
  const int bh = (y < 32) ? pairA(x) : pairB(x);
  const int kt = (y < 32) ? y : (y - 32);
  const int b = bh >> 2, hh = bh & 3;
  const int tid = threadIdx.x;
  const size_t tb = (size_t)(bh * 32 + kt) * 16384;
  char* ktile = khat + tb;
  char* qtile = qhat + tb;
  char* vtile = vT + tb;
  const float Gtv = Gt_arr[bh * 32 + kt];

  // K + Q part: coalesced row reads (16 lanes cover one 512B row)
  {
    const int dc8 = tid & 15;          // d-chunk of 8
    const int s4  = tid >> 4;          // 0..15
    const int ks = dc8 >> 1, hi = dc8 & 1;
    #pragma unroll
    for (int jj = 0; jj < 4; ++jj) {
      const int s = s4 + 16 * jj;      // 0..63
      const int sg = kt * 64 + s;
      const float cf = __expf(g_arr[(size_t)bh * S_LEN + sg] - Gtv);
      const int unit = (((s >> 5) * 8 + ks) * 2 + hi) * 32 + (s & 31);
      const float* kr = k + ((size_t)(b * S_LEN + sg)) * D_DIM + hh * DHEAD + dc8 * 8;
      float4 x0 = *(const float4*)kr;
      float4 x1 = *(const float4*)(kr + 4);
      uint4 u;
      u.x = pkh(x0.x * cf, x0.y * cf);
      u.y = pkh(x0.z * cf, x0.w * cf);
      u.z = pkh(x1.x * cf, x1.y * cf);
      u.w = pkh(x1.z * cf, x1.w * cf);
      *(uint4*)(ktile + unit * 16) = u;
      const float* qr = q + ((size_t)(b * S_LEN + sg)) * D_DIM + hh * DHEAD + dc8 * 8;
      float4 y0 = *(const float4*)qr;
      float4 y1 = *(const float4*)(qr + 4);
      uint4 uq;
      uq.x = pkh(y0.x * SCALE_QK, y0.y * SCALE_QK);
      uq.y = pkh(y0.z * SCALE_QK, y0.w * SCALE_QK);
      uq.z = pkh(y1.x * SCALE_QK, y1.y * SCALE_QK);
      uq.w = pkh(y1.z * SCALE_QK, y1.w * SCALE_QK);
      *(uint4*)(qtile + unit * 16) = uq;
    }
  }
  // V part: column gather (coalesced across d)
  {
    const int d   = tid & 127;
    const int scg = tid >> 7;          // 0..1
    const int df = d >> 5, lo = d & 31;
    #pragma unroll
    for (int jj = 0; jj < 4; ++jj) {
      const int sc8 = scg + 2 * jj;    // 0..7
      const int c = sc8 >> 1, hi = sc8 & 1;
      const float* vr = v + ((size_t)(b * S_LEN + kt * 64 + sc8 * 8)) * D_DIM + hh * DHEAD + d;
      float vv[8];
      #pragma unroll
      for (int t = 0; t < 8; ++t) vv[t] = vr[(size_t)t * D_DIM];
      uint4 u;
      u.x = pkh(vv[0], vv[1]); u.y = pkh(vv[2], vv[3]);
      u.z = pkh(vv[4], vv[5]); u.w = pkh(vv[6], vv[7]);
      const int unit = ((df * 4 + c) * 2 + hi) * 32 + lo;
      *(uint4*)(vtile + unit * 16) = u;
    }
  }
}

// ---------------- Kernel 4: barrier-free MFMA attention, K-prefetch ----------
// grid (8, 64): x = XCD slot; y<32 -> bh=pairA(x), p=y; else bh=pairB(x).
// Blocks id and id+256 share a CU -> one light-head + one heavy-head block/CU.
// 4 waves = 4-way s-split of the 128-kt tile; K frags double-buffered in regs
// one step ahead (unroll-by-2, static indexing); V issued at step top, consumed
// after QK. No barriers until epilogue.
__global__ __launch_bounds__(256, 2) void attn_kernel(
    const char* __restrict__ qhat, const char* __restrict__ khat, const char* __restrict__ vT,
    const float* __restrict__ M_arr, const float* __restrict__ bs_arr,
    const float* __restrict__ Gt_arr,
    const float* __restrict__ ln_w, const float* __restrict__ ln_b,
    float* __restrict__ out)
{
  __shared__ float cb[12480];         // 3 waves x (4x16x64) h + 3x64 rowsum
  const int xb = blockIdx.x, y = blockIdx.y;
  const int bh = (y < 32) ? pairA(xb) : pairB(xb);
  const int p  = (y < 32) ? y : (y - 32);
  const int b = bh >> 2, hh = bh & 3;
  const int tid = threadIdx.x;
  const int w = tid >> 6, lane = tid & 63, lo = lane & 31, hi = lane >> 5;
  const int sh = w;                   // s-quarter 0..3
  const int s64 = sh >> 1, s32 = sh & 1;
  const int lb16 = (hi * 32 + lo) * 16;

  const char* gq = qhat + (size_t)bh * 524288;
  const char* gk = khat + (size_t)bh * 524288;
  const char* gv = vT   + (size_t)bh * 524288;
  const float* Mb  = M_arr  + (size_t)bh * S_LEN;
  const float* bsb = bs_arr + (size_t)bh * S_LEN;
  const float* Gtb = Gt_arr + bh * 32;

  const float GtReg = Gtb[lo];        // lane i holds Gt64[i]

  for (int half = 0; half < 2; ++half) {
    const int j  = half ? p : (63 - p);
    const int tg = 32 * j + lo;
    const float Mt = Mb[tg];
    const float em = __expf(-(bsb[tg] + Mt));
    const float M0 = Mb[32 * j];
    const int ktLast = (32 * j + 31) >> 7;     // 128-kt tiles
    int kts = 0;
    while (kts < ktLast &&
           fmaxf(Gtb[2 * kts], Gtb[2 * kts + 1]) < M0 - 25.f) ++kts;

    // Q fragments: coalesced from qhat
    f16x8 qf[8];
    const char* qt = gq + (size_t)(j >> 1) * 16384;
    #pragma unroll
    for (int ks = 0; ks < 8; ++ks)
      qf[ks] = *(const f16x8*)(qt + ((j & 1) * 8 + ks) * 1024 + lb16);

    f32x16 h0 = {}, h1 = {}, h2 = {}, h3 = {};
    float rowsum = 0.f;

    auto load_k = [&](uint4* kf, int kt2) {
      const char* kb = gk + (size_t)(2 * kt2 + s64) * 16384;
      #pragma unroll
      for (int ks = 0; ks < 8; ++ks)
        kf[ks] = *(const uint4*)(kb + (s32 * 8 + ks) * 1024 + lb16);
    };

    auto step = [&](int kt, uint4* kf, uint4* kfn, bool pref) {
      const char* vb = gv + (size_t)(2 * kt + s64) * 16384;
      uint4 vf[8];
      #pragma unroll
      for (int df = 0; df < 4; ++df)
        #pragma unroll
        for (int ks2 = 0; ks2 < 2; ++ks2)
          vf[df * 2 + ks2] = *(const uint4*)(vb + ((df * 4 + 2 * s32 + ks2)) * 1024 + lb16);
      if (pref) load_k(kfn, kt + 1);

      const float Gtv = __shfl(GtReg, 2 * kt + s64);
      const float rf = __expf(Gtv - Mt);

      f32x16 sacc0 = {}, sacc1 = {};
      __builtin_amdgcn_s_setprio(1);
      #pragma unroll
      for (int ks = 0; ks < 4; ++ks) {
        sacc0 = __builtin_amdgcn_mfma_f32_32x32x16_f16(
            __builtin_bit_cast(f16x8, kf[2 * ks]), qf[2 * ks], sacc0, 0, 0, 0);
        sacc1 = __builtin_amdgcn_mfma_f32_32x32x16_f16(
            __builtin_bit_cast(f16x8, kf[2 * ks + 1]), qf[2 * ks + 1], sacc1, 0, 0, 0);
      }
      __builtin_amdgcn_s_setprio(0);

      const bool last = (kt == ktLast);
      const int bnd = tg - 128 * kt;
      float tsum = 0.f;
      uint32_t pk[8];
      #pragma unroll
      for (int rr = 0; rr < 8; ++rr) {
        float v0 = (sacc0[2 * rr] + sacc1[2 * rr]) * rf;
        float v1 = (sacc0[2 * rr + 1] + sacc1[2 * rr + 1]) * rf;
        if (last) {
          int sl0 = 32 * sh + ((2 * rr) & 3) + 8 * (rr >> 1) + 4 * hi;
          if (sl0 > bnd) v0 = 0.f;
          if (sl0 + 1 > bnd) v1 = 0.f;
        }
        tsum += v0 + v1;
        pk[rr] = pkh(v0, v1);
      }
      rowsum += tsum + __shfl_xor(tsum, 32);
      uint32_t sw[8];
      #pragma unroll
      for (int rr = 0; rr < 8; ++rr) sw[rr] = __shfl_xor(pk[rr], 32);
      uint4 f0, f1;
      f0.x = hi ? sw[2] : pk[0];  f0.y = hi ? sw[3] : pk[1];
      f0.z = hi ? pk[2] : sw[0];  f0.w = hi ? pk[3] : sw[1];
      f1.x = hi ? sw[6] : pk[4];  f1.y = hi ? sw[7] : pk[5];
      f1.z = hi ? pk[6] : sw[4];  f1.w = hi ? pk[7] : sw[5];
      f16x8 f0h = __builtin_bit_cast(f16x8, f0);
      f16x8 f1h = __builtin_bit_cast(f16x8, f1);

      __builtin_amdgcn_s_setprio(1);
      h0 = __builtin_amdgcn_mfma_f32_32x32x16_f16(__builtin_bit_cast(f16x8, vf[0]), f0h, h0, 0, 0, 0);
      h1 = __builtin_amdgcn_mfma_f32_32x32x16_f16(__builtin_bit_cast(f16x8, vf[2]), f0h, h1, 0, 0, 0);
      h2 = __builtin_amdgcn_mfma_f32_32x32x16_f16(__builtin_bit_cast(f16x8, vf[4]), f0h, h2, 0, 0, 0);
      h3 = __builtin_amdgcn_mfma_f32_32x32x16_f16(__builtin_bit_cast(f16x8, vf[6]), f0h, h3, 0, 0, 0);
      h0 = __builtin_amdgcn_mfma_f32_32x32x16_f16(__builtin_bit_cast(f16x8, vf[1]), f1h, h0, 0, 0, 0);
      h1 = __builtin_amdgcn_mfma_f32_32x32x16_f16(__builtin_bit_cast(f16x8, vf[3]), f1h, h1, 0, 0, 0);
      h2 = __builtin_amdgcn_mfma_f32_32x32x16_f16(__builtin_bit_cast(f16x8, vf[5]), f1h, h2, 0, 0, 0);
      h3 = __builtin_amdgcn_mfma_f32_32x32x16_f16(__builtin_bit_cast(f16x8, vf[7]), f1h, h3, 0, 0, 0);
      __builtin_amdgcn_s_setprio(0);
    };

    uint4 ka[8], kb2[8];
    load_k(ka, kts);
    for (int kt = kts; kt <= ktLast; kt += 2) {
      step(kt, ka, kb2, kt + 1 <= ktLast);
      if (kt + 1 > ktLast) break;
      step(kt + 1, kb2, ka, kt + 2 <= ktLast);
    }

    // ---- epilogue: waves 1-3 dump partial h; wave 0 combines + LN + store ----
    if (w != 0) {
      const int wb = (w - 1) * 4096;
      #pragma unroll
      for (int r = 0; r < 16; ++r) {
        cb[wb +    0 + r * 64 + lane] = h0[r];
        cb[wb + 1024 + r * 64 + lane] = h1[r];
        cb[wb + 2048 + r * 64 + lane] = h2[r];
        cb[wb + 3072 + r * 64 + lane] = h3[r];
      }
      cb[12288 + (w - 1) * 64 + lane] = rowsum;
    }
    __syncthreads();
    if (w == 0) {
      #pragma unroll
      for (int u = 0; u < 3; ++u) {
        const int ub = u * 4096;
        #pragma unroll
        for (int r = 0; r < 16; ++r) {
          h0[r] += cb[ub +    0 + r * 64 + lane];
          h1[r] += cb[ub + 1024 + r * 64 + lane];
          h2[r] += cb[ub + 2048 + r * 64 + lane];
          h3[r] += cb[ub + 3072 + r * 64 + lane];
        }
      }
      rowsum += cb[12288 + lane] + cb[12352 + lane] + cb[12416 + lane];
      float n = fmaxf(fabsf(rowsum), em);
      float invn = 1.f / (n + 5e-5f);
      float s1 = 0.f, s2 = 0.f;
      #pragma unroll
      for (int r = 0; r < 16; ++r) {
        float x0 = h0[r] * invn, x1 = h1[r] * invn;
        float x2 = h2[r] * invn, x3 = h3[r] * invn;
        h0[r] = x0; h1[r] = x1; h2[r] = x2; h3[r] = x3;
        s1 += x0 + x1 + x2 + x3;
        s2 += x0 * x0 + x1 * x1 + x2 * x2 + x3 * x3;
      }
      s1 += __shfl_xor(s1, 32);
      s2 += __shfl_xor(s2, 32);
      float mu = s1 * (1.f / 128.f);
      float var = s2 * (1.f / 128.f) - mu * mu;
      float rstd = rsqrtf(var + 1e-3f);
      float* orow = out + ((size_t)(b * S_LEN) + tg) * D_DIM + hh * DHEAD;
      #pragma unroll
      for (int df = 0; df < 4; ++df) {
        #pragma unroll
        for (int rq = 0; rq < 4; ++rq) {
          int dbase = 32 * df + 8 * rq + 4 * hi;
          float4 wv = *(const float4*)(ln_w + hh * DHEAD + dbase);
          float4 bv = *(const float4*)(ln_b + hh * DHEAD + dbase);
          float v0, v1, v2, v3;
          if (df == 0)      { v0 = h0[rq*4+0]; v1 = h0[rq*4+1]; v2 = h0[rq*4+2]; v3 = h0[rq*4+3]; }
          else if (df == 1) { v0 = h1[rq*4+0]; v1 = h1[rq*4+1]; v2 = h1[rq*4+2]; v3 = h1[rq*4+3]; }
          else if (df == 2) { v0 = h2[rq*4+0]; v1 = h2[rq*4+1]; v2 = h2[rq*4+2]; v3 = h2[rq*4+3]; }
          else              { v0 = h3[rq*4+0]; v1 = h3[rq*4+1]; v2 = h3[rq*4+2]; v3 = h3[rq*4+3]; }
          float4 o;
          o.x = (v0 - mu) * rstd * (1.f + wv.x) + bv.x;
          o.y = (v1 - mu) * rstd * (1.f + wv.y) + bv.y;
          o.z = (v2 - mu) * rstd * (1.f + wv.z) + bv.z;
          o.w = (v3 - mu) * rstd * (1.f + wv.w) + bv.w;
          *(float4*)(orow + dbase) = o;
        }
      }
    }
    __syncthreads();   // cb reused next half
  }
}

extern "C" void kernel_launch(void* const* d_in, const int* in_sizes, int n_in,
                              void* d_out, int out_size, void* d_ws, size_t ws_size,
                              hipStream_t stream) {
  (void)in_sizes; (void)n_in; (void)out_size; (void)ws_size;
  const float* q    = (const float*)d_in[0];
  const float* k    = (const float*)d_in[1];
  const float* v    = (const float*)d_in[2];
  const float* Wi   = (const float*)d_in[3];
  const float* bi   = (const float*)d_in[4];
  const float* Wf   = (const float*)d_in[5];
  const float* bf   = (const float*)d_in[6];
  const float* ln_w = (const float*)d_in[7];
  const float* ln_b = (const float*)d_in[8];

  char* wsb = (char*)d_ws;
  float* ipre = (float*)(wsb + 0);
  float* fpre = (float*)(wsb + 131072);
  float* garr = (float*)(wsb + 262144);
  float* Marr = (float*)(wsb + 393216);
  float* bsum = (float*)(wsb + 524288);
  float* Gt   = (float*)(wsb + 655360);       // 16*32 floats
  char* kh = wsb + 1048576;                    // 8MB
  char* vt = wsb + 1048576 + 8388608;          // 8MB
  char* qh = wsb + 1048576 + 16777216;         // 8MB

  gate_kernel<<<2048, 256, 0, stream>>>(q, k, v, Wi, bi, Wf, bf, ipre, fpre);
  scan_kernel<<<16, 256, 0, stream>>>(ipre, fpre, garr, Marr, bsum, Gt);
  convert_kernel<<<dim3(8, 64), 256, 0, stream>>>(q, k, v, garr, Gt, qh, kh, vt);
  attn_kernel<<<dim3(8, 64), 256, 0, stream>>>(qh, kh, vt, Marr, bsum, Gt,
                                               ln_w, ln_b, (float*)d_out);
}

// Round 12
// 89.827 us; speedup vs baseline: 1.1425x; 1.1425x over previous
//
#include <hip/hip_runtime.h>
#include <cstddef>
#include <cstdint>

#define S_LEN 2048
#define D_DIM 512
#define NHEAD 4
#define DHEAD 128
#define BH_CNT 16
#define SCALE_QK 0.08838834764831845f

typedef _Float16 f16;
typedef _Float16 f16x8 __attribute__((ext_vector_type(8)));
typedef float f32x16 __attribute__((ext_vector_type(16)));

__device__ __forceinline__ unsigned pkh(float a, float b) {
  auto r = __builtin_amdgcn_cvt_pkrtz(a, b);   // __fp16 ext_vector_type(2)
  return __builtin_bit_cast(unsigned, r);
}

// ---------------- Kernel 1: gate preactivations ----------------
__global__ __launch_bounds__(256) void gate_kernel(
    const float* __restrict__ q, const float* __restrict__ k, const float* __restrict__ v,
    const float* __restrict__ Wi, const float* __restrict__ bi,
    const float* __restrict__ Wf, const float* __restrict__ bf,
    float* __restrict__ ipre, float* __restrict__ fpre)
{
  const int wave = threadIdx.x >> 6;
  const int lane = threadIdx.x & 63;
  const int pos  = blockIdx.x * 4 + wave;
  const int b = pos >> 11;
  const int s = pos & 2047;
  const float* qp = q + (size_t)pos * D_DIM;
  const float* kp = k + (size_t)pos * D_DIM;
  const float* vp = v + (size_t)pos * D_DIM;

  float acc[8] = {0.f,0.f,0.f,0.f,0.f,0.f,0.f,0.f};
  #pragma unroll
  for (int j = 0; j < 24; ++j) {
    int e = lane + (j << 6);
    float x;
    if (e < 512)       x = qp[e];
    else if (e < 1024) x = kp[e - 512];
    else               x = vp[e - 1024];
    #pragma unroll
    for (int h = 0; h < 4; ++h) {
      acc[h]     = fmaf(x, Wi[h * 1536 + e], acc[h]);
      acc[4 + h] = fmaf(x, Wf[h * 1536 + e], acc[4 + h]);
    }
  }
  #pragma unroll
  for (int off = 32; off > 0; off >>= 1) {
    #pragma unroll
    for (int a = 0; a < 8; ++a) acc[a] += __shfl_down(acc[a], off);
  }
  if (lane == 0) {
    #pragma unroll
    for (int h = 0; h < 4; ++h) {
      ipre[(size_t)(b * 4 + h) * S_LEN + s] = acc[h] + bi[h];
      fpre[(size_t)(b * 4 + h) * S_LEN + s] = acc[4 + h] + bf[h];
    }
  }
}

// ---------------- Kernel 2: single-pass register scans ----------------
__global__ __launch_bounds__(256) void scan_kernel(
    const float* __restrict__ ipre, const float* __restrict__ fpre,
    float* __restrict__ g_out, float* __restrict__ M_out,
    float* __restrict__ bsum_out, float* __restrict__ Gt_out)
{
  __shared__ float wsh[8];
  const int bh = blockIdx.x;
  const int tid = threadIdx.x, lane = tid & 63, wv = tid >> 6;
  const int base = tid * 8;
  const float* fp = fpre + (size_t)bh * S_LEN;
  const float* ip = ipre + (size_t)bh * S_LEN;

  float x[8], ls[8];
  float4 a0 = *(const float4*)(fp + base), a1 = *(const float4*)(fp + base + 4);
  x[0]=a0.x; x[1]=a0.y; x[2]=a0.z; x[3]=a0.w;
  x[4]=a1.x; x[5]=a1.y; x[6]=a1.z; x[7]=a1.w;
  float run = 0.f;
  #pragma unroll
  for (int i = 0; i < 8; ++i) {
    float lsv = fminf(x[i], 0.f) - log1pf(expf(-fabsf(x[i])));
    run += lsv; ls[i] = run;
  }
  float sc = run;
  #pragma unroll
  for (int off = 1; off < 64; off <<= 1) {
    float o = __shfl_up(sc, off);
    if (lane >= off) sc += o;
  }
  if (lane == 63) wsh[wv] = sc;
  __syncthreads();
  float woff = 0.f;
  #pragma unroll
  for (int u = 0; u < 4; ++u) if (u < wv) woff += wsh[u];
  const float ex = woff + (sc - run);

  float4 i0 = *(const float4*)(ip + base), i1 = *(const float4*)(ip + base + 4);
  float iv[8];
  iv[0]=i0.x; iv[1]=i0.y; iv[2]=i0.z; iv[3]=i0.w;
  iv[4]=i1.x; iv[5]=i1.y; iv[6]=i1.z; iv[7]=i1.w;
  float g[8], bc[8], pm[8];
  float runm = -3.0e38f;
  #pragma unroll
  for (int i = 0; i < 8; ++i) {
    bc[i] = ex + ls[i];
    g[i] = iv[i] - bc[i];
    runm = fmaxf(runm, g[i]);
    pm[i] = runm;
  }
  *(float4*)(bsum_out + (size_t)bh * S_LEN + base)     = make_float4(bc[0],bc[1],bc[2],bc[3]);
  *(float4*)(bsum_out + (size_t)bh * S_LEN + base + 4) = make_float4(bc[4],bc[5],bc[6],bc[7]);
  *(float4*)(g_out + (size_t)bh * S_LEN + base)        = make_float4(g[0],g[1],g[2],g[3]);
  *(float4*)(g_out + (size_t)bh * S_LEN + base + 4)    = make_float4(g[4],g[5],g[6],g[7]);

  float t8 = runm;
  t8 = fmaxf(t8, __shfl_xor(t8, 1));
  t8 = fmaxf(t8, __shfl_xor(t8, 2));
  t8 = fmaxf(t8, __shfl_xor(t8, 4));
  if ((tid & 7) == 0) Gt_out[bh * 32 + (tid >> 3)] = t8;

  float scm = runm;
  #pragma unroll
  for (int off = 1; off < 64; off <<= 1) {
    float o = __shfl_up(scm, off);
    if (lane >= off) scm = fmaxf(scm, o);
  }
  if (lane == 63) wsh[4 + wv] = scm;
  __syncthreads();
  float wmo = -3.0e38f;
  #pragma unroll
  for (int u = 0; u < 4; ++u) if (u < wv) wmo = fmaxf(wmo, wsh[4 + u]);
  float prev = __shfl_up(scm, 1);
  if (lane == 0) prev = -3.0e38f;
  const float exm = fmaxf(wmo, prev);
  float M[8];
  #pragma unroll
  for (int i = 0; i < 8; ++i) M[i] = fmaxf(exm, pm[i]);
  *(float4*)(M_out + (size_t)bh * S_LEN + base)     = make_float4(M[0],M[1],M[2],M[3]);
  *(float4*)(M_out + (size_t)bh * S_LEN + base + 4) = make_float4(M[4],M[5],M[6],M[7]);
}

// head-complementary bh pairing: XCD x serves pairA(x) (head 0/1) and
// pairB(x) (head 3/2) so per-XCD work is balanced despite head-dependent skip.
__device__ __forceinline__ int pairA(int x) { return (x >> 1) * 4 + (x & 1); }
__device__ __forceinline__ int pairB(int x) { return (x >> 1) * 4 + 3 - (x & 1); }

// ---------------- Kernel 3: fp16 conversion, fragment-linear, XCD-matched ----
__global__ __launch_bounds__(256) void convert_kernel(
    const float* __restrict__ q, const float* __restrict__ k, const float* __restrict__ v,
    const float* __restrict__ g_arr, const float* __restrict__ Gt_arr,
    char* __restrict__ qhat, char* __restrict__ khat, char* __restrict__ vT)
{
  const int x = blockIdx.x, y = blockIdx.y;
  const int bh = (y < 32) ? pairA(x) : pairB(x);
  const int kt = (y < 32) ? y : (y - 32);
  const int b = bh >> 2, hh = bh & 3;
  const int tid = threadIdx.x;
  const size_t tb = (size_t)(bh * 32 + kt) * 16384;
  char* ktile = khat + tb;
  char* qtile = qhat + tb;
  char* vtile = vT + tb;
  const float Gtv = Gt_arr[bh * 32 + kt];

  // K + Q part: coalesced row reads (16 lanes cover one 512B row)
  {
    const int dc8 = tid & 15;          // d-chunk of 8
    const int s4  = tid >> 4;          // 0..15
    const int ks = dc8 >> 1, hi = dc8 & 1;
    #pragma unroll
    for (int jj = 0; jj < 4; ++jj) {
      const int s = s4 + 16 * jj;      // 0..63
      const int sg = kt * 64 + s;
      const float cf = __expf(g_arr[(size_t)bh * S_LEN + sg] - Gtv);
      const int unit = (((s >> 5) * 8 + ks) * 2 + hi) * 32 + (s & 31);
      const float* kr = k + ((size_t)(b * S_LEN + sg)) * D_DIM + hh * DHEAD + dc8 * 8;
      float4 x0 = *(const float4*)kr;
      float4 x1 = *(const float4*)(kr + 4);
      uint4 u;
      u.x = pkh(x0.x * cf, x0.y * cf);
      u.y = pkh(x0.z * cf, x0.w * cf);
      u.z = pkh(x1.x * cf, x1.y * cf);
      u.w = pkh(x1.z * cf, x1.w * cf);
      *(uint4*)(ktile + unit * 16) = u;
      const float* qr = q + ((size_t)(b * S_LEN + sg)) * D_DIM + hh * DHEAD + dc8 * 8;
      float4 y0 = *(const float4*)qr;
      float4 y1 = *(const float4*)(qr + 4);
      uint4 uq;
      uq.x = pkh(y0.x * SCALE_QK, y0.y * SCALE_QK);
      uq.y = pkh(y0.z * SCALE_QK, y0.w * SCALE_QK);
      uq.z = pkh(y1.x * SCALE_QK, y1.y * SCALE_QK);
      uq.w = pkh(y1.z * SCALE_QK, y1.w * SCALE_QK);
      *(uint4*)(qtile + unit * 16) = uq;
    }
  }
  // V part: column gather (coalesced across d)
  {
    const int d   = tid & 127;
    const int scg = tid >> 7;          // 0..1
    const int df = d >> 5, lo = d & 31;
    #pragma unroll
    for (int jj = 0; jj < 4; ++jj) {
      const int sc8 = scg + 2 * jj;    // 0..7
      const int c = sc8 >> 1, hi = sc8 & 1;
      const float* vr = v + ((size_t)(b * S_LEN + kt * 64 + sc8 * 8)) * D_DIM + hh * DHEAD + d;
      float vv[8];
      #pragma unroll
      for (int t = 0; t < 8; ++t) vv[t] = vr[(size_t)t * D_DIM];
      uint4 u;
      u.x = pkh(vv[0], vv[1]); u.y = pkh(vv[2], vv[3]);
      u.z = pkh(vv[4], vv[5]); u.w = pkh(vv[6], vv[7]);
      const int unit = ((df * 4 + c) * 2 + hi) * 32 + lo;
      *(uint4*)(vtile + unit * 16) = u;
    }
  }
}

#define MFMA_(a, b, c) __builtin_amdgcn_mfma_f32_32x32x16_f16(__builtin_bit_cast(f16x8, a), (b), (c), 0, 0, 0)

#define LOAD_K(P, kt2) do {                                                   \
    const char* kbp_ = gk + (size_t)(2 * (kt2) + s64) * 16384 + s32 * 8192 + lb16; \
    P##0 = *(const uint4*)(kbp_ + 0 * 1024);                                  \
    P##1 = *(const uint4*)(kbp_ + 1 * 1024);                                  \
    P##2 = *(const uint4*)(kbp_ + 2 * 1024);                                  \
    P##3 = *(const uint4*)(kbp_ + 3 * 1024);                                  \
    P##4 = *(const uint4*)(kbp_ + 4 * 1024);                                  \
    P##5 = *(const uint4*)(kbp_ + 5 * 1024);                                  \
    P##6 = *(const uint4*)(kbp_ + 6 * 1024);                                  \
    P##7 = *(const uint4*)(kbp_ + 7 * 1024);                                  \
  } while (0)

#define STEP(KP, KN, ktv, pref) do {                                          \
    const int kt_ = (ktv);                                                    \
    const char* vb_ = gv + (size_t)(2 * kt_ + s64) * 16384 + 2 * s32 * 1024 + lb16; \
    uint4 vf0 = *(const uint4*)(vb_ + 0 * 1024);                              \
    uint4 vf1 = *(const uint4*)(vb_ + 1 * 1024);                              \
    uint4 vf2 = *(const uint4*)(vb_ + 4 * 1024);                              \
    uint4 vf3 = *(const uint4*)(vb_ + 5 * 1024);                              \
    uint4 vf4 = *(const uint4*)(vb_ + 8 * 1024);                              \
    uint4 vf5 = *(const uint4*)(vb_ + 9 * 1024);                              \
    uint4 vf6 = *(const uint4*)(vb_ + 12 * 1024);                             \
    uint4 vf7 = *(const uint4*)(vb_ + 13 * 1024);                             \
    if (pref) LOAD_K(KN, kt_ + 1);                                            \
    const float Gtv_ = __shfl(GtReg, 2 * kt_ + s64);                          \
    const float rf_ = __expf(Gtv_ - Mt);                                      \
    f32x16 sacc0 = {}, sacc1 = {};                                            \
    __builtin_amdgcn_s_setprio(1);                                            \
    sacc0 = MFMA_(KP##0, qf[0], sacc0); sacc1 = MFMA_(KP##1, qf[1], sacc1);   \
    sacc0 = MFMA_(KP##2, qf[2], sacc0); sacc1 = MFMA_(KP##3, qf[3], sacc1);   \
    sacc0 = MFMA_(KP##4, qf[4], sacc0); sacc1 = MFMA_(KP##5, qf[5], sacc1);   \
    sacc0 = MFMA_(KP##6, qf[6], sacc0); sacc1 = MFMA_(KP##7, qf[7], sacc1);   \
    __builtin_amdgcn_s_setprio(0);                                            \
    const bool last_ = (kt_ == ktLast);                                       \
    const int bnd_ = tg - 128 * kt_;                                          \
    float tsum_ = 0.f;                                                        \
    uint32_t pk_[8];                                                          \
    _Pragma("unroll")                                                         \
    for (int rr = 0; rr < 8; ++rr) {                                          \
      float v0_ = (sacc0[2 * rr] + sacc1[2 * rr]) * rf_;                      \
      float v1_ = (sacc0[2 * rr + 1] + sacc1[2 * rr + 1]) * rf_;              \
      if (last_) {                                                            \
        int sl0_ = 32 * sh + ((2 * rr) & 3) + 8 * (rr >> 1) + 4 * hi;         \
        if (sl0_ > bnd_) v0_ = 0.f;                                           \
        if (sl0_ + 1 > bnd_) v1_ = 0.f;                                       \
      }                                                                       \
      tsum_ += v0_ + v1_;                                                     \
      pk_[rr] = pkh(v0_, v1_);                                                \
    }                                                                         \
    rowsum += tsum_ + __shfl_xor(tsum_, 32);                                  \
    uint32_t sw_[8];                                                          \
    _Pragma("unroll")                                                         \
    for (int rr = 0; rr < 8; ++rr) sw_[rr] = __shfl_xor(pk_[rr], 32);         \
    uint4 f0_, f1_;                                                           \
    f0_.x = hi ? sw_[2] : pk_[0];  f0_.y = hi ? sw_[3] : pk_[1];              \
    f0_.z = hi ? pk_[2] : sw_[0];  f0_.w = hi ? pk_[3] : sw_[1];              \
    f1_.x = hi ? sw_[6] : pk_[4];  f1_.y = hi ? sw_[7] : pk_[5];              \
    f1_.z = hi ? pk_[6] : sw_[4];  f1_.w = hi ? pk_[7] : sw_[5];              \
    f16x8 f0h_ = __builtin_bit_cast(f16x8, f0_);                              \
    f16x8 f1h_ = __builtin_bit_cast(f16x8, f1_);                              \
    __builtin_amdgcn_s_setprio(1);                                            \
    h0 = MFMA_(vf0, f0h_, h0); h1 = MFMA_(vf2, f0h_, h1);                     \
    h2 = MFMA_(vf4, f0h_, h2); h3 = MFMA_(vf6, f0h_, h3);                     \
    h0 = MFMA_(vf1, f1h_, h0); h1 = MFMA_(vf3, f1h_, h1);                     \
    h2 = MFMA_(vf5, f1h_, h2); h3 = MFMA_(vf7, f1h_, h3);                     \
    __builtin_amdgcn_s_setprio(0);                                            \
  } while (0)

// ---------------- Kernel 4: barrier-free MFMA attention, reg K-prefetch ------
// grid (8, 64): x = XCD slot; y<32 -> bh=pairA(x), p=y; else bh=pairB(x).
// 4 waves = 4-way s-split of the 128-kt tile; K frags double-buffered in NAMED
// registers one step ahead (macro-expanded, no pointer decay -> no scratch).
__global__ __launch_bounds__(256, 2) void attn_kernel(
    const char* __restrict__ qhat, const char* __restrict__ khat, const char* __restrict__ vT,
    const float* __restrict__ M_arr, const float* __restrict__ bs_arr,
    const float* __restrict__ Gt_arr,
    const float* __restrict__ ln_w, const float* __restrict__ ln_b,
    float* __restrict__ out)
{
  __shared__ float cb[12480];         // 3 waves x (4x16x64) h + 3x64 rowsum
  const int xb = blockIdx.x, y = blockIdx.y;
  const int bh = (y < 32) ? pairA(xb) : pairB(xb);
  const int p  = (y < 32) ? y : (y - 32);
  const int b = bh >> 2, hh = bh & 3;
  const int tid = threadIdx.x;
  const int w = tid >> 6, lane = tid & 63, lo = lane & 31, hi = lane >> 5;
  const int sh = w;                   // s-quarter 0..3
  const int s64 = sh >> 1, s32 = sh & 1;
  const int lb16 = (hi * 32 + lo) * 16;

  const char* gq = qhat + (size_t)bh * 524288;
  const char* gk = khat + (size_t)bh * 524288;
  const char* gv = vT   + (size_t)bh * 524288;
  const float* Mb  = M_arr  + (size_t)bh * S_LEN;
  const float* bsb = bs_arr + (size_t)bh * S_LEN;
  const float* Gtb = Gt_arr + bh * 32;

  const float GtReg = Gtb[lo];        // lane i holds Gt64[i]

  for (int half = 0; half < 2; ++half) {
    const int j  = half ? p : (63 - p);
    const int tg = 32 * j + lo;
    const float Mt = Mb[tg];
    const float em = __expf(-(bsb[tg] + Mt));
    const float M0 = Mb[32 * j];
    const int ktLast = (32 * j + 31) >> 7;     // 128-kt tiles
    int kts = 0;
    while (kts < ktLast &&
           fmaxf(Gtb[2 * kts], Gtb[2 * kts + 1]) < M0 - 25.f) ++kts;

    // Q fragments: coalesced from qhat
    f16x8 qf[8];
    const char* qt = gq + (size_t)(j >> 1) * 16384;
    #pragma unroll
    for (int ks = 0; ks < 8; ++ks)
      qf[ks] = *(const f16x8*)(qt + ((j & 1) * 8 + ks) * 1024 + lb16);

    f32x16 h0 = {}, h1 = {}, h2 = {}, h3 = {};
    float rowsum = 0.f;

    uint4 kA0, kA1, kA2, kA3, kA4, kA5, kA6, kA7;
    uint4 kB0, kB1, kB2, kB3, kB4, kB5, kB6, kB7;
    LOAD_K(kA, kts);
    for (int kt = kts; kt <= ktLast; kt += 2) {
      STEP(kA, kB, kt, kt + 1 <= ktLast);
      if (kt + 1 > ktLast) break;
      STEP(kB, kA, kt + 1, kt + 2 <= ktLast);
    }

    // ---- epilogue: waves 1-3 dump partial h; wave 0 combines + LN + store ----
    if (w != 0) {
      const int wb = (w - 1) * 4096;
      #pragma unroll
      for (int r = 0; r < 16; ++r) {
        cb[wb +    0 + r * 64 + lane] = h0[r];
        cb[wb + 1024 + r * 64 + lane] = h1[r];
        cb[wb + 2048 + r * 64 + lane] = h2[r];
        cb[wb + 3072 + r * 64 + lane] = h3[r];
      }
      cb[12288 + (w - 1) * 64 + lane] = rowsum;
    }
    __syncthreads();
    if (w == 0) {
      #pragma unroll
      for (int u = 0; u < 3; ++u) {
        const int ub = u * 4096;
        #pragma unroll
        for (int r = 0; r < 16; ++r) {
          h0[r] += cb[ub +    0 + r * 64 + lane];
          h1[r] += cb[ub + 1024 + r * 64 + lane];
          h2[r] += cb[ub + 2048 + r * 64 + lane];
          h3[r] += cb[ub + 3072 + r * 64 + lane];
        }
      }
      rowsum += cb[12288 + lane] + cb[12352 + lane] + cb[12416 + lane];
      float n = fmaxf(fabsf(rowsum), em);
      float invn = 1.f / (n + 5e-5f);
      float s1 = 0.f, s2 = 0.f;
      #pragma unroll
      for (int r = 0; r < 16; ++r) {
        float x0 = h0[r] * invn, x1 = h1[r] * invn;
        float x2 = h2[r] * invn, x3 = h3[r] * invn;
        h0[r] = x0; h1[r] = x1; h2[r] = x2; h3[r] = x3;
        s1 += x0 + x1 + x2 + x3;
        s2 += x0 * x0 + x1 * x1 + x2 * x2 + x3 * x3;
      }
      s1 += __shfl_xor(s1, 32);
      s2 += __shfl_xor(s2, 32);
      float mu = s1 * (1.f / 128.f);
      float var = s2 * (1.f / 128.f) - mu * mu;
      float rstd = rsqrtf(var + 1e-3f);
      float* orow = out + ((size_t)(b * S_LEN) + tg) * D_DIM + hh * DHEAD;
      #pragma unroll
      for (int df = 0; df < 4; ++df) {
        #pragma unroll
        for (int rq = 0; rq < 4; ++rq) {
          int dbase = 32 * df + 8 * rq + 4 * hi;
          float4 wv = *(const float4*)(ln_w + hh * DHEAD + dbase);
          float4 bv = *(const float4*)(ln_b + hh * DHEAD + dbase);
          float v0, v1, v2, v3;
          if (df == 0)      { v0 = h0[rq*4+0]; v1 = h0[rq*4+1]; v2 = h0[rq*4+2]; v3 = h0[rq*4+3]; }
          else if (df == 1) { v0 = h1[rq*4+0]; v1 = h1[rq*4+1]; v2 = h1[rq*4+2]; v3 = h1[rq*4+3]; }
          else if (df == 2) { v0 = h2[rq*4+0]; v1 = h2[rq*4+1]; v2 = h2[rq*4+2]; v3 = h2[rq*4+3]; }
          else              { v0 = h3[rq*4+0]; v1 = h3[rq*4+1]; v2 = h3[rq*4+2]; v3 = h3[rq*4+3]; }
          float4 o;
          o.x = (v0 - mu) * rstd * (1.f + wv.x) + bv.x;
          o.y = (v1 - mu) * rstd * (1.f + wv.y) + bv.y;
          o.z = (v2 - mu) * rstd * (1.f + wv.z) + bv.z;
          o.w = (v3 - mu) * rstd * (1.f + wv.w) + bv.w;
          *(float4*)(orow + dbase) = o;
        }
      }
    }
    __syncthreads();   // cb reused next half
  }
}

extern "C" void kernel_launch(void* const* d_in, const int* in_sizes, int n_in,
                              void* d_out, int out_size, void* d_ws, size_t ws_size,
                              hipStream_t stream) {
  (void)in_sizes; (void)n_in; (void)out_size; (void)ws_size;
  const float* q    = (const float*)d_in[0];
  const float* k    = (const float*)d_in[1];
  const float* v    = (const float*)d_in[2];
  const float* Wi   = (const float*)d_in[3];
  const float* bi   = (const float*)d_in[4];
  const float* Wf   = (const float*)d_in[5];
  const float* bf   = (const float*)d_in[6];
  const float* ln_w = (const float*)d_in[7];
  const float* ln_b = (const float*)d_in[8];

  char* wsb = (char*)d_ws;
  float* ipre = (float*)(wsb + 0);
  float* fpre = (float*)(wsb + 131072);
  float* garr = (float*)(wsb + 262144);
  float* Marr = (float*)(wsb + 393216);
  float* bsum = (float*)(wsb + 524288);
  float* Gt   = (float*)(wsb + 655360);       // 16*32 floats
  char* kh = wsb + 1048576;                    // 8MB
  char* vt = wsb + 1048576 + 8388608;          // 8MB
  char* qh = wsb + 1048576 + 16777216;         // 8MB

  gate_kernel<<<2048, 256, 0, stream>>>(q, k, v, Wi, bi, Wf, bf, ipre, fpre);
  scan_kernel<<<16, 256, 0, stream>>>(ipre, fpre, garr, Marr, bsum, Gt);
  convert_kernel<<<dim3(8, 64), 256, 0, stream>>>(q, k, v, garr, Gt, qh, kh, vt);
  attn_kernel<<<dim3(8, 64), 256, 0, stream>>>(qh, kh, vt, Marr, bsum, Gt,
                                               ln_w, ln_b, (float*)d_out);
}

// Round 13
// 76.716 us; speedup vs baseline: 1.3378x; 1.1709x over previous
//
#include <hip/hip_runtime.h>
#include <cstddef>
#include <cstdint>

#define S_LEN 2048
#define D_DIM 512
#define NHEAD 4
#define DHEAD 128
#define BH_CNT 16
#define SCALE_QK 0.08838834764831845f

typedef _Float16 f16;
typedef _Float16 f16x8 __attribute__((ext_vector_type(8)));
typedef float f32x16 __attribute__((ext_vector_type(16)));

__device__ __forceinline__ unsigned pkh(float a, float b) {
  auto r = __builtin_amdgcn_cvt_pkrtz(a, b);   // __fp16 ext_vector_type(2)
  return __builtin_bit_cast(unsigned, r);
}

// ---------------- Kernel 1: gate preactivations ----------------
__global__ __launch_bounds__(256) void gate_kernel(
    const float* __restrict__ q, const float* __restrict__ k, const float* __restrict__ v,
    const float* __restrict__ Wi, const float* __restrict__ bi,
    const float* __restrict__ Wf, const float* __restrict__ bf,
    float* __restrict__ ipre, float* __restrict__ fpre)
{
  const int wave = threadIdx.x >> 6;
  const int lane = threadIdx.x & 63;
  const int pos  = blockIdx.x * 4 + wave;
  const int b = pos >> 11;
  const int s = pos & 2047;
  const float* qp = q + (size_t)pos * D_DIM;
  const float* kp = k + (size_t)pos * D_DIM;
  const float* vp = v + (size_t)pos * D_DIM;

  float acc[8] = {0.f,0.f,0.f,0.f,0.f,0.f,0.f,0.f};
  #pragma unroll
  for (int j = 0; j < 24; ++j) {
    int e = lane + (j << 6);
    float x;
    if (e < 512)       x = qp[e];
    else if (e < 1024) x = kp[e - 512];
    else               x = vp[e - 1024];
    #pragma unroll
    for (int h = 0; h < 4; ++h) {
      acc[h]     = fmaf(x, Wi[h * 1536 + e], acc[h]);
      acc[4 + h] = fmaf(x, Wf[h * 1536 + e], acc[4 + h]);
    }
  }
  #pragma unroll
  for (int off = 32; off > 0; off >>= 1) {
    #pragma unroll
    for (int a = 0; a < 8; ++a) acc[a] += __shfl_down(acc[a], off);
  }
  if (lane == 0) {
    #pragma unroll
    for (int h = 0; h < 4; ++h) {
      ipre[(size_t)(b * 4 + h) * S_LEN + s] = acc[h] + bi[h];
      fpre[(size_t)(b * 4 + h) * S_LEN + s] = acc[4 + h] + bf[h];
    }
  }
}

// ---------------- Kernel 2: single-pass register scans ----------------
__global__ __launch_bounds__(256) void scan_kernel(
    const float* __restrict__ ipre, const float* __restrict__ fpre,
    float* __restrict__ g_out, float* __restrict__ M_out,
    float* __restrict__ bsum_out, float* __restrict__ Gt_out)
{
  __shared__ float wsh[8];
  const int bh = blockIdx.x;
  const int tid = threadIdx.x, lane = tid & 63, wv = tid >> 6;
  const int base = tid * 8;
  const float* fp = fpre + (size_t)bh * S_LEN;
  const float* ip = ipre + (size_t)bh * S_LEN;

  float x[8], ls[8];
  float4 a0 = *(const float4*)(fp + base), a1 = *(const float4*)(fp + base + 4);
  x[0]=a0.x; x[1]=a0.y; x[2]=a0.z; x[3]=a0.w;
  x[4]=a1.x; x[5]=a1.y; x[6]=a1.z; x[7]=a1.w;
  float run = 0.f;
  #pragma unroll
  for (int i = 0; i < 8; ++i) {
    float lsv = fminf(x[i], 0.f) - log1pf(expf(-fabsf(x[i])));
    run += lsv; ls[i] = run;
  }
  float sc = run;
  #pragma unroll
  for (int off = 1; off < 64; off <<= 1) {
    float o = __shfl_up(sc, off);
    if (lane >= off) sc += o;
  }
  if (lane == 63) wsh[wv] = sc;
  __syncthreads();
  float woff = 0.f;
  #pragma unroll
  for (int u = 0; u < 4; ++u) if (u < wv) woff += wsh[u];
  const float ex = woff + (sc - run);

  float4 i0 = *(const float4*)(ip + base), i1 = *(const float4*)(ip + base + 4);
  float iv[8];
  iv[0]=i0.x; iv[1]=i0.y; iv[2]=i0.z; iv[3]=i0.w;
  iv[4]=i1.x; iv[5]=i1.y; iv[6]=i1.z; iv[7]=i1.w;
  float g[8], bc[8], pm[8];
  float runm = -3.0e38f;
  #pragma unroll
  for (int i = 0; i < 8; ++i) {
    bc[i] = ex + ls[i];
    g[i] = iv[i] - bc[i];
    runm = fmaxf(runm, g[i]);
    pm[i] = runm;
  }
  *(float4*)(bsum_out + (size_t)bh * S_LEN + base)     = make_float4(bc[0],bc[1],bc[2],bc[3]);
  *(float4*)(bsum_out + (size_t)bh * S_LEN + base + 4) = make_float4(bc[4],bc[5],bc[6],bc[7]);
  *(float4*)(g_out + (size_t)bh * S_LEN + base)        = make_float4(g[0],g[1],g[2],g[3]);
  *(float4*)(g_out + (size_t)bh * S_LEN + base + 4)    = make_float4(g[4],g[5],g[6],g[7]);

  float t8 = runm;
  t8 = fmaxf(t8, __shfl_xor(t8, 1));
  t8 = fmaxf(t8, __shfl_xor(t8, 2));
  t8 = fmaxf(t8, __shfl_xor(t8, 4));
  if ((tid & 7) == 0) Gt_out[bh * 32 + (tid >> 3)] = t8;

  float scm = runm;
  #pragma unroll
  for (int off = 1; off < 64; off <<= 1) {
    float o = __shfl_up(scm, off);
    if (lane >= off) scm = fmaxf(scm, o);
  }
  if (lane == 63) wsh[4 + wv] = scm;
  __syncthreads();
  float wmo = -3.0e38f;
  #pragma unroll
  for (int u = 0; u < 4; ++u) if (u < wv) wmo = fmaxf(wmo, wsh[4 + u]);
  float prev = __shfl_up(scm, 1);
  if (lane == 0) prev = -3.0e38f;
  const float exm = fmaxf(wmo, prev);
  float M[8];
  #pragma unroll
  for (int i = 0; i < 8; ++i) M[i] = fmaxf(exm, pm[i]);
  *(float4*)(M_out + (size_t)bh * S_LEN + base)     = make_float4(M[0],M[1],M[2],M[3]);
  *(float4*)(M_out + (size_t)bh * S_LEN + base + 4) = make_float4(M[4],M[5],M[6],M[7]);
}

// head-complementary bh pairing: XCD x serves pairA(x) (head 0/1) and
// pairB(x) (head 3/2) so per-XCD work is balanced despite head-dependent skip.
__device__ __forceinline__ int pairA(int x) { return (x >> 1) * 4 + (x & 1); }
__device__ __forceinline__ int pairB(int x) { return (x >> 1) * 4 + 3 - (x & 1); }

// ---------------- Kernel 3: fp16 conversion, fragment-linear, XCD-matched ----
__global__ __launch_bounds__(256) void convert_kernel(
    const float* __restrict__ q, const float* __restrict__ k, const float* __restrict__ v,
    const float* __restrict__ g_arr, const float* __restrict__ Gt_arr,
    char* __restrict__ qhat, char* __restrict__ khat, char* __restrict__ vT)
{
  const int x = blockIdx.x, y = blockIdx.y;
  const int bh = (y < 32) ? pairA(x) : pairB(x);
  const int kt = (y < 32) ? y : (y - 32);
  const int b = bh >> 2, hh = bh & 3;
  const int tid = threadIdx.x;
  const size_t tb = (size_t)(bh * 32 + kt) * 16384;
  char* ktile = khat + tb;
  char* qtile = qhat + tb;
  char* vtile = vT + tb;
  const float Gtv = Gt_arr[bh * 32 + kt];

  // K + Q part: coalesced row reads (16 lanes cover one 512B row)
  {
    const int dc8 = tid & 15;          // d-chunk of 8
    const int s4  = tid >> 4;          // 0..15
    const int ks = dc8 >> 1, hi = dc8 & 1;
    #pragma unroll
    for (int jj = 0; jj < 4; ++jj) {
      const int s = s4 + 16 * jj;      // 0..63
      const int sg = kt * 64 + s;
      const float cf = __expf(g_arr[(size_t)bh * S_LEN + sg] - Gtv);
      const int unit = (((s >> 5) * 8 + ks) * 2 + hi) * 32 + (s & 31);
      const float* kr = k + ((size_t)(b * S_LEN + sg)) * D_DIM + hh * DHEAD + dc8 * 8;
      float4 x0 = *(const float4*)kr;
      float4 x1 = *(const float4*)(kr + 4);
      uint4 u;
      u.x = pkh(x0.x * cf, x0.y * cf);
      u.y = pkh(x0.z * cf, x0.w * cf);
      u.z = pkh(x1.x * cf, x1.y * cf);
      u.w = pkh(x1.z * cf, x1.w * cf);
      *(uint4*)(ktile + unit * 16) = u;
      const float* qr = q + ((size_t)(b * S_LEN + sg)) * D_DIM + hh * DHEAD + dc8 * 8;
      float4 y0 = *(const float4*)qr;
      float4 y1 = *(const float4*)(qr + 4);
      uint4 uq;
      uq.x = pkh(y0.x * SCALE_QK, y0.y * SCALE_QK);
      uq.y = pkh(y0.z * SCALE_QK, y0.w * SCALE_QK);
      uq.z = pkh(y1.x * SCALE_QK, y1.y * SCALE_QK);
      uq.w = pkh(y1.z * SCALE_QK, y1.w * SCALE_QK);
      *(uint4*)(qtile + unit * 16) = uq;
    }
  }
  // V part: column gather (coalesced across d)
  {
    const int d   = tid & 127;
    const int scg = tid >> 7;          // 0..1
    const int df = d >> 5, lo = d & 31;
    #pragma unroll
    for (int jj = 0; jj < 4; ++jj) {
      const int sc8 = scg + 2 * jj;    // 0..7
      const int c = sc8 >> 1, hi = sc8 & 1;
      const float* vr = v + ((size_t)(b * S_LEN + kt * 64 + sc8 * 8)) * D_DIM + hh * DHEAD + d;
      float vv[8];
      #pragma unroll
      for (int t = 0; t < 8; ++t) vv[t] = vr[(size_t)t * D_DIM];
      uint4 u;
      u.x = pkh(vv[0], vv[1]); u.y = pkh(vv[2], vv[3]);
      u.z = pkh(vv[4], vv[5]); u.w = pkh(vv[6], vv[7]);
      const int unit = ((df * 4 + c) * 2 + hi) * 32 + lo;
      *(uint4*)(vtile + unit * 16) = u;
    }
  }
}

#define MFMA_(a, b, c) __builtin_amdgcn_mfma_f32_32x32x16_f16(__builtin_bit_cast(f16x8, a), (b), (c), 0, 0, 0)

// ---------------- Kernel 4: barrier-free MFMA attention, budget-fit ----------
// grid (8, 64): x = XCD slot; y<32 -> bh=pairA(x), p=y; else bh=pairB(x).
// 4 waves = 4-way s-split of the 128-kt tile. No K prefetch, single QK
// accumulator: peak arch-VGPR ~127 + 64 AGPR h -> no scratch spill at 2 blk/CU.
__global__ __launch_bounds__(256, 2) void attn_kernel(
    const char* __restrict__ qhat, const char* __restrict__ khat, const char* __restrict__ vT,
    const float* __restrict__ M_arr, const float* __restrict__ bs_arr,
    const float* __restrict__ Gt_arr,
    const float* __restrict__ ln_w, const float* __restrict__ ln_b,
    float* __restrict__ out)
{
  __shared__ float cb[12480];         // 3 waves x (4x16x64) h + 3x64 rowsum
  const int xb = blockIdx.x, y = blockIdx.y;
  const int bh = (y < 32) ? pairA(xb) : pairB(xb);
  const int p  = (y < 32) ? y : (y - 32);
  const int b = bh >> 2, hh = bh & 3;
  const int tid = threadIdx.x;
  const int w = tid >> 6, lane = tid & 63, lo = lane & 31, hi = lane >> 5;
  const int sh = w;                   // s-quarter 0..3
  const int s64 = sh >> 1, s32 = sh & 1;
  const int lb16 = (hi * 32 + lo) * 16;

  const char* gq = qhat + (size_t)bh * 524288;
  const char* gk = khat + (size_t)bh * 524288;
  const char* gv = vT   + (size_t)bh * 524288;
  const float* Mb  = M_arr  + (size_t)bh * S_LEN;
  const float* bsb = bs_arr + (size_t)bh * S_LEN;
  const float* Gtb = Gt_arr + bh * 32;

  const float GtReg = Gtb[lo];        // lane i holds Gt64[i]

  for (int half = 0; half < 2; ++half) {
    const int j  = half ? p : (63 - p);
    const int tg = 32 * j + lo;
    const float Mt = Mb[tg];
    const float em = __expf(-(bsb[tg] + Mt));
    const float M0 = Mb[32 * j];
    const int ktLast = (32 * j + 31) >> 7;     // 128-kt tiles
    int kts = 0;
    while (kts < ktLast &&
           fmaxf(Gtb[2 * kts], Gtb[2 * kts + 1]) < M0 - 25.f) ++kts;

    // Q fragments: coalesced from qhat
    f16x8 qf[8];
    const char* qt = gq + (size_t)(j >> 1) * 16384;
    #pragma unroll
    for (int ks = 0; ks < 8; ++ks)
      qf[ks] = *(const f16x8*)(qt + ((j & 1) * 8 + ks) * 1024 + lb16);

    f32x16 h0 = {}, h1 = {}, h2 = {}, h3 = {};
    float rowsum = 0.f;

    for (int kt = kts; kt <= ktLast; ++kt) {
      const char* kbp = gk + (size_t)(2 * kt + s64) * 16384 + s32 * 8192 + lb16;
      uint4 kf0 = *(const uint4*)(kbp + 0 * 1024);
      uint4 kf1 = *(const uint4*)(kbp + 1 * 1024);
      uint4 kf2 = *(const uint4*)(kbp + 2 * 1024);
      uint4 kf3 = *(const uint4*)(kbp + 3 * 1024);
      uint4 kf4 = *(const uint4*)(kbp + 4 * 1024);
      uint4 kf5 = *(const uint4*)(kbp + 5 * 1024);
      uint4 kf6 = *(const uint4*)(kbp + 6 * 1024);
      uint4 kf7 = *(const uint4*)(kbp + 7 * 1024);
      const char* vbp = gv + (size_t)(2 * kt + s64) * 16384 + 2 * s32 * 1024 + lb16;
      uint4 vf0 = *(const uint4*)(vbp + 0 * 1024);
      uint4 vf1 = *(const uint4*)(vbp + 1 * 1024);
      uint4 vf2 = *(const uint4*)(vbp + 4 * 1024);
      uint4 vf3 = *(const uint4*)(vbp + 5 * 1024);
      uint4 vf4 = *(const uint4*)(vbp + 8 * 1024);
      uint4 vf5 = *(const uint4*)(vbp + 9 * 1024);
      uint4 vf6 = *(const uint4*)(vbp + 12 * 1024);
      uint4 vf7 = *(const uint4*)(vbp + 13 * 1024);

      const float Gtv = __shfl(GtReg, 2 * kt + s64);
      const float rf = __expf(Gtv - Mt);

      f32x16 sacc = {};
      __builtin_amdgcn_s_setprio(1);
      sacc = MFMA_(kf0, qf[0], sacc);
      sacc = MFMA_(kf1, qf[1], sacc);
      sacc = MFMA_(kf2, qf[2], sacc);
      sacc = MFMA_(kf3, qf[3], sacc);
      sacc = MFMA_(kf4, qf[4], sacc);
      sacc = MFMA_(kf5, qf[5], sacc);
      sacc = MFMA_(kf6, qf[6], sacc);
      sacc = MFMA_(kf7, qf[7], sacc);
      __builtin_amdgcn_s_setprio(0);

      const bool last = (kt == ktLast);
      const int bnd = tg - 128 * kt;
      float tsum = 0.f;
      uint32_t pk[8];
      #pragma unroll
      for (int rr = 0; rr < 8; ++rr) {
        float v0 = sacc[2 * rr] * rf;
        float v1 = sacc[2 * rr + 1] * rf;
        if (last) {
          int sl0 = 32 * sh + ((2 * rr) & 3) + 8 * (rr >> 1) + 4 * hi;
          if (sl0 > bnd) v0 = 0.f;
          if (sl0 + 1 > bnd) v1 = 0.f;
        }
        tsum += v0 + v1;
        pk[rr] = pkh(v0, v1);
      }
      rowsum += tsum + __shfl_xor(tsum, 32);
      uint32_t sw[8];
      #pragma unroll
      for (int rr = 0; rr < 8; ++rr) sw[rr] = __shfl_xor(pk[rr], 32);
      uint4 f0, f1;
      f0.x = hi ? sw[2] : pk[0];  f0.y = hi ? sw[3] : pk[1];
      f0.z = hi ? pk[2] : sw[0];  f0.w = hi ? pk[3] : sw[1];
      f1.x = hi ? sw[6] : pk[4];  f1.y = hi ? sw[7] : pk[5];
      f1.z = hi ? pk[6] : sw[4];  f1.w = hi ? pk[7] : sw[5];
      f16x8 f0h = __builtin_bit_cast(f16x8, f0);
      f16x8 f1h = __builtin_bit_cast(f16x8, f1);

      __builtin_amdgcn_s_setprio(1);
      h0 = MFMA_(vf0, f0h, h0);
      h1 = MFMA_(vf2, f0h, h1);
      h2 = MFMA_(vf4, f0h, h2);
      h3 = MFMA_(vf6, f0h, h3);
      h0 = MFMA_(vf1, f1h, h0);
      h1 = MFMA_(vf3, f1h, h1);
      h2 = MFMA_(vf5, f1h, h2);
      h3 = MFMA_(vf7, f1h, h3);
      __builtin_amdgcn_s_setprio(0);
    }

    // ---- epilogue: waves 1-3 dump partial h; wave 0 combines + LN + store ----
    if (w != 0) {
      const int wb = (w - 1) * 4096;
      #pragma unroll
      for (int r = 0; r < 16; ++r) {
        cb[wb +    0 + r * 64 + lane] = h0[r];
        cb[wb + 1024 + r * 64 + lane] = h1[r];
        cb[wb + 2048 + r * 64 + lane] = h2[r];
        cb[wb + 3072 + r * 64 + lane] = h3[r];
      }
      cb[12288 + (w - 1) * 64 + lane] = rowsum;
    }
    __syncthreads();
    if (w == 0) {
      #pragma unroll
      for (int u = 0; u < 3; ++u) {
        const int ub = u * 4096;
        #pragma unroll
        for (int r = 0; r < 16; ++r) {
          h0[r] += cb[ub +    0 + r * 64 + lane];
          h1[r] += cb[ub + 1024 + r * 64 + lane];
          h2[r] += cb[ub + 2048 + r * 64 + lane];
          h3[r] += cb[ub + 3072 + r * 64 + lane];
        }
      }
      rowsum += cb[12288 + lane] + cb[12352 + lane] + cb[12416 + lane];
      float n = fmaxf(fabsf(rowsum), em);
      float invn = 1.f / (n + 5e-5f);
      float s1 = 0.f, s2 = 0.f;
      #pragma unroll
      for (int r = 0; r < 16; ++r) {
        float x0 = h0[r] * invn, x1 = h1[r] * invn;
        float x2 = h2[r] * invn, x3 = h3[r] * invn;
        h0[r] = x0; h1[r] = x1; h2[r] = x2; h3[r] = x3;
        s1 += x0 + x1 + x2 + x3;
        s2 += x0 * x0 + x1 * x1 + x2 * x2 + x3 * x3;
      }
      s1 += __shfl_xor(s1, 32);
      s2 += __shfl_xor(s2, 32);
      float mu = s1 * (1.f / 128.f);
      float var = s2 * (1.f / 128.f) - mu * mu;
      float rstd = rsqrtf(var + 1e-3f);
      float* orow = out + ((size_t)(b * S_LEN) + tg) * D_DIM + hh * DHEAD;
      #pragma unroll
      for (int df = 0; df < 4; ++df) {
        #pragma unroll
        for (int rq = 0; rq < 4; ++rq) {
          int dbase = 32 * df + 8 * rq + 4 * hi;
          float4 wv = *(const float4*)(ln_w + hh * DHEAD + dbase);
          float4 bv = *(const float4*)(ln_b + hh * DHEAD + dbase);
          float v0, v1, v2, v3;
          if (df == 0)      { v0 = h0[rq*4+0]; v1 = h0[rq*4+1]; v2 = h0[rq*4+2]; v3 = h0[rq*4+3]; }
          else if (df == 1) { v0 = h1[rq*4+0]; v1 = h1[rq*4+1]; v2 = h1[rq*4+2]; v3 = h1[rq*4+3]; }
          else if (df == 2) { v0 = h2[rq*4+0]; v1 = h2[rq*4+1]; v2 = h2[rq*4+2]; v3 = h2[rq*4+3]; }
          else              { v0 = h3[rq*4+0]; v1 = h3[rq*4+1]; v2 = h3[rq*4+2]; v3 = h3[rq*4+3]; }
          float4 o;
          o.x = (v0 - mu) * rstd * (1.f + wv.x) + bv.x;
          o.y = (v1 - mu) * rstd * (1.f + wv.y) + bv.y;
          o.z = (v2 - mu) * rstd * (1.f + wv.z) + bv.z;
          o.w = (v3 - mu) * rstd * (1.f + wv.w) + bv.w;
          *(float4*)(orow + dbase) = o;
        }
      }
    }
    __syncthreads();   // cb reused next half
  }
}

extern "C" void kernel_launch(void* const* d_in, const int* in_sizes, int n_in,
                              void* d_out, int out_size, void* d_ws, size_t ws_size,
                              hipStream_t stream) {
  (void)in_sizes; (void)n_in; (void)out_size; (void)ws_size;
  const float* q    = (const float*)d_in[0];
  const float* k    = (const float*)d_in[1];
  const float* v    = (const float*)d_in[2];
  const float* Wi   = (const float*)d_in[3];
  const float* bi   = (const float*)d_in[4];
  const float* Wf   = (const float*)d_in[5];
  const float* bf   = (const float*)d_in[6];
  const float* ln_w = (const float*)d_in[7];
  const float* ln_b = (const float*)d_in[8];

  char* wsb = (char*)d_ws;
  float* ipre = (float*)(wsb + 0);
  float* fpre = (float*)(wsb + 131072);
  float* garr = (float*)(wsb + 262144);
  float* Marr = (float*)(wsb + 393216);
  float* bsum = (float*)(wsb + 524288);
  float* Gt   = (float*)(wsb + 655360);       // 16*32 floats
  char* kh = wsb + 1048576;                    // 8MB
  char* vt = wsb + 1048576 + 8388608;          // 8MB
  char* qh = wsb + 1048576 + 16777216;         // 8MB

  gate_kernel<<<2048, 256, 0, stream>>>(q, k, v, Wi, bi, Wf, bf, ipre, fpre);
  scan_kernel<<<16, 256, 0, stream>>>(ipre, fpre, garr, Marr, bsum, Gt);
  convert_kernel<<<dim3(8, 64), 256, 0, stream>>>(q, k, v, garr, Gt, qh, kh, vt);
  attn_kernel<<<dim3(8, 64), 256, 0, stream>>>(qh, kh, vt, Marr, bsum, Gt,
                                               ln_w, ln_b, (float*)d_out);
}